// Round 1
// baseline (3346.597 us; speedup 1.0000x reference)
//
#include <hip/hip_runtime.h>
#include <hip/hip_bf16.h>

#define NN 50000
#define NE 600000
#define NG 512
#define DH 128

__global__ __launch_bounds__(256) void k_zero(float* p, int n) {
    int i = blockIdx.x * 256 + threadIdx.x;
    if (i < n) p[i] = 0.0f;
}

__global__ __launch_bounds__(256) void k_set1(float* p, int n) {
    int i = blockIdx.x * 256 + threadIdx.x;
    if (i < n) p[i] = 1.0f;
}

__global__ __launch_bounds__(256) void k_degcount(const int* __restrict__ dst, float* __restrict__ deg) {
    int e = blockIdx.x * 256 + threadIdx.x;
    if (e < NE) atomicAdd(&deg[dst[e]], 1.0f);
}

__global__ __launch_bounds__(256) void k_invsqrt(float* p, int n) {
    int i = blockIdx.x * 256 + threadIdx.x;
    if (i < n) p[i] = 1.0f / sqrtf(p[i]);
}

__global__ __launch_bounds__(256) void k_counts(const int* __restrict__ batch, float* __restrict__ counts) {
    int i = blockIdx.x * 256 + threadIdx.x;
    if (i < NN) atomicAdd(&counts[batch[i]], 1.0f);
}

// C[M,128] = A[M,128] @ W[128,128], f32. Block: 64 rows x 128 cols, 256 thr, thread: 4x8.
__global__ __launch_bounds__(256) void k_gemm128(const float* __restrict__ A,
                                                 const float* __restrict__ W,
                                                 float* __restrict__ C, int M) {
    __shared__ float As[64][20];    // pad 20: A-read 2-way conflict only
    __shared__ float Bs[16][132];   // pad 132 (mult of 4) for aligned float4
    int tid = threadIdx.x;
    int r0 = blockIdx.x * 64;
    int tr = tid >> 4, tc = tid & 15;

    float acc[4][8];
#pragma unroll
    for (int i = 0; i < 4; ++i)
#pragma unroll
        for (int j = 0; j < 8; ++j) acc[i][j] = 0.f;

    int arow = tid >> 2, ac4 = (tid & 3) * 4;

    for (int k0 = 0; k0 < 128; k0 += 16) {
        float4 av = make_float4(0.f, 0.f, 0.f, 0.f);
        int gr = r0 + arow;
        if (gr < M) av = *(const float4*)&A[gr * 128 + k0 + ac4];
        *(float4*)&As[arow][ac4] = av;
#pragma unroll
        for (int t = 0; t < 2; ++t) {
            int idx = tid + t * 256;
            int bk = idx >> 5, bc4 = (idx & 31) * 4;
            *(float4*)&Bs[bk][bc4] = *(const float4*)&W[(k0 + bk) * 128 + bc4];
        }
        __syncthreads();
#pragma unroll
        for (int kk = 0; kk < 16; ++kk) {
            float a[4];
#pragma unroll
            for (int i = 0; i < 4; ++i) a[i] = As[tr * 4 + i][kk];
            float4 bv0 = *(float4*)&Bs[kk][tc * 8];
            float4 bv1 = *(float4*)&Bs[kk][tc * 8 + 4];
            float b[8] = {bv0.x, bv0.y, bv0.z, bv0.w, bv1.x, bv1.y, bv1.z, bv1.w};
#pragma unroll
            for (int i = 0; i < 4; ++i)
#pragma unroll
                for (int j = 0; j < 8; ++j) acc[i][j] = fmaf(a[i], b[j], acc[i][j]);
        }
        __syncthreads();
    }

#pragma unroll
    for (int i = 0; i < 4; ++i) {
        int gr = r0 + tr * 4 + i;
        if (gr < M) {
            float4 o0 = make_float4(acc[i][0], acc[i][1], acc[i][2], acc[i][3]);
            float4 o1 = make_float4(acc[i][4], acc[i][5], acc[i][6], acc[i][7]);
            *(float4*)&C[gr * 128 + tc * 8] = o0;
            *(float4*)&C[gr * 128 + tc * 8 + 4] = o1;
        }
    }
}

// agg[i][:] = hw[i][:] * dis[i]^2   (self-loop contribution)
__global__ __launch_bounds__(256) void k_self(const float4* __restrict__ hw,
                                              const float* __restrict__ dis,
                                              float4* __restrict__ agg) {
    int t = blockIdx.x * 256 + threadIdx.x;
    if (t >= NN * 32) return;
    int node = t >> 5;
    float d = dis[node];
    float w = d * d;
    float4 v = hw[t];
    agg[t] = make_float4(v.x * w, v.y * w, v.z * w, v.w * w);
}

// agg[dst] += hw[src] * dis[src]*dis[dst]  (32 threads/edge, float4 each)
__global__ __launch_bounds__(256) void k_scatter(const float* __restrict__ hw,
                                                 const int* __restrict__ src,
                                                 const int* __restrict__ dst,
                                                 const float* __restrict__ dis,
                                                 float* __restrict__ agg) {
    int t = blockIdx.x * 256 + threadIdx.x;
    int e = t >> 5;
    if (e >= NE) return;
    int f4 = t & 31;
    int s = src[e], d = dst[e];
    float w = dis[s] * dis[d];
    float4 v = ((const float4*)hw)[s * 32 + f4];
    float* o = agg + d * 128 + f4 * 4;
    atomicAdd(o + 0, v.x * w);
    atomicAdd(o + 1, v.y * w);
    atomicAdd(o + 2, v.z * w);
    atomicAdd(o + 3, v.w * w);
}

__global__ __launch_bounds__(256) void k_bias_relu(float4* __restrict__ agg, const float* __restrict__ b) {
    int t = blockIdx.x * 256 + threadIdx.x;
    if (t >= NN * 32) return;
    int c4 = (t & 31) * 4;
    float4 v = agg[t];
    v.x = fmaxf(v.x + b[c4 + 0], 0.f);
    v.y = fmaxf(v.y + b[c4 + 1], 0.f);
    v.z = fmaxf(v.z + b[c4 + 2], 0.f);
    v.w = fmaxf(v.w + b[c4 + 3], 0.f);
    agg[t] = v;
}

// fused: bias+relu of layer2 output, then atomic mean-pool accumulate
__global__ __launch_bounds__(256) void k_pool(const float4* __restrict__ agg,
                                              const int* __restrict__ batch,
                                              const float* __restrict__ b,
                                              float* __restrict__ sums) {
    int t = blockIdx.x * 256 + threadIdx.x;
    if (t >= NN * 32) return;
    int node = t >> 5;
    int c4 = (t & 31) * 4;
    int g = batch[node];
    float4 v = agg[t];
    float r0 = fmaxf(v.x + b[c4 + 0], 0.f);
    float r1 = fmaxf(v.y + b[c4 + 1], 0.f);
    float r2 = fmaxf(v.z + b[c4 + 2], 0.f);
    float r3 = fmaxf(v.w + b[c4 + 3], 0.f);
    float* o = sums + g * 128 + c4;
    atomicAdd(o + 0, r0);
    atomicAdd(o + 1, r1);
    atomicAdd(o + 2, r2);
    atomicAdd(o + 3, r3);
}

// 512 blocks x 64 threads: pooled = sums/count; logits = pooled@Wf + bf; log_softmax
__global__ __launch_bounds__(64) void k_head(const float* __restrict__ sums,
                                             const float* __restrict__ counts,
                                             const float* __restrict__ Wf,
                                             const float* __restrict__ bf,
                                             float* __restrict__ out) {
    int g = blockIdx.x;
    int l = threadIdx.x;
    float inv = 1.0f / fmaxf(counts[g], 1.0f);
    float p0 = sums[g * 128 + l] * inv;
    float p1 = sums[g * 128 + 64 + l] * inv;
    float logit[10];
#pragma unroll
    for (int o = 0; o < 10; ++o) {
        float part = p0 * Wf[l * 10 + o] + p1 * Wf[(l + 64) * 10 + o];
#pragma unroll
        for (int s = 32; s > 0; s >>= 1) part += __shfl_xor(part, s);
        logit[o] = part + bf[o];
    }
    if (l == 0) {
        float m = logit[0];
#pragma unroll
        for (int o = 1; o < 10; ++o) m = fmaxf(m, logit[o]);
        float sum = 0.f;
#pragma unroll
        for (int o = 0; o < 10; ++o) sum += expf(logit[o] - m);
        float lse = m + logf(sum);
#pragma unroll
        for (int o = 0; o < 10; ++o) out[g * 10 + o] = logit[o] - lse;
    }
}

extern "C" void kernel_launch(void* const* d_in, const int* in_sizes, int n_in,
                              void* d_out, int out_size, void* d_ws, size_t ws_size,
                              hipStream_t stream) {
    const float* x     = (const float*)d_in[0];
    const int*   ei    = (const int*)d_in[1];
    const int*   batch = (const int*)d_in[2];
    const float* W0 = (const float*)d_in[3];
    const float* b0 = (const float*)d_in[4];
    const float* W1 = (const float*)d_in[5];
    const float* b1 = (const float*)d_in[6];
    const float* W2 = (const float*)d_in[7];
    const float* b2 = (const float*)d_in[8];
    const float* Wf = (const float*)d_in[9];
    const float* bf = (const float*)d_in[10];
    float* out = (float*)d_out;

    float* ws = (float*)d_ws;
    float* dis    = ws;                     // 50000 (padded to 50048)
    float* sums   = ws + 50048;             // 512*128 = 65536
    float* counts = ws + 115584;            // 512
    float* bufA   = ws + 116096;            // 50000*128
    float* bufB   = bufA + NN * DH;         // 50000*128

    const int* src = ei;
    const int* dst = ei + NE;

    // degree/norm + zero pooled accumulators
    k_zero<<<(65536 + 512 + 255) / 256, 256, 0, stream>>>(sums, 65536 + 512);
    k_set1<<<196, 256, 0, stream>>>(dis, NN);
    k_degcount<<<2344, 256, 0, stream>>>(dst, dis);
    k_invsqrt<<<196, 256, 0, stream>>>(dis, NN);
    k_counts<<<196, 256, 0, stream>>>(batch, counts);

    // layer 0: x -> bufB (h@W0) -> bufA (aggregated) -> relu
    k_gemm128<<<(NN + 63) / 64, 256, 0, stream>>>(x, W0, bufB, NN);
    k_self<<<6250, 256, 0, stream>>>((const float4*)bufB, dis, (float4*)bufA);
    k_scatter<<<75000, 256, 0, stream>>>(bufB, src, dst, dis, bufA);
    k_bias_relu<<<6250, 256, 0, stream>>>((float4*)bufA, b0);

    // layer 1
    k_gemm128<<<(NN + 63) / 64, 256, 0, stream>>>(bufA, W1, bufB, NN);
    k_self<<<6250, 256, 0, stream>>>((const float4*)bufB, dis, (float4*)bufA);
    k_scatter<<<75000, 256, 0, stream>>>(bufB, src, dst, dis, bufA);
    k_bias_relu<<<6250, 256, 0, stream>>>((float4*)bufA, b1);

    // layer 2 (bias+relu fused into pooling)
    k_gemm128<<<(NN + 63) / 64, 256, 0, stream>>>(bufA, W2, bufB, NN);
    k_self<<<6250, 256, 0, stream>>>((const float4*)bufB, dis, (float4*)bufA);
    k_scatter<<<75000, 256, 0, stream>>>(bufB, src, dst, dis, bufA);
    k_pool<<<6250, 256, 0, stream>>>((const float4*)bufA, batch, b2, sums);

    k_head<<<512, 64, 0, stream>>>(sums, counts, Wf, bf, out);
}

// Round 2
// 446.010 us; speedup vs baseline: 7.5034x; 7.5034x over previous
//
#include <hip/hip_runtime.h>
#include <hip/hip_bf16.h>

#define NN 50000
#define NE 600000
#define NG 512
#define DH 128

__global__ __launch_bounds__(256) void k_zero(float* p, int n) {
    int i = blockIdx.x * 256 + threadIdx.x;
    if (i < n) p[i] = 0.0f;
}

// in-degree histogram (int)
__global__ __launch_bounds__(256) void k_hist(const int* __restrict__ dst, int* __restrict__ deg) {
    int e = blockIdx.x * 256 + threadIdx.x;
    if (e < NE) atomicAdd(&deg[dst[e]], 1);
}

__global__ __launch_bounds__(256) void k_counts(const int* __restrict__ batch, float* __restrict__ counts) {
    int i = blockIdx.x * 256 + threadIdx.x;
    if (i < NN) atomicAdd(&counts[batch[i]], 1.0f);
}

// allocate contiguous CSR row per node; compute dis = 1/sqrt(deg+1)
__global__ __launch_bounds__(256) void k_alloc(const int* __restrict__ deg, int* __restrict__ gcur,
                                               int* __restrict__ rowstart, int* __restrict__ cursor,
                                               float* __restrict__ dis) {
    int i = blockIdx.x * 256 + threadIdx.x;
    if (i >= NN) return;
    int d = deg[i];
    int st = atomicAdd(gcur, d);
    rowstart[i] = st;
    cursor[i] = st;
    dis[i] = 1.0f / sqrtf((float)(d + 1));
}

// fill CSR slots: src id + edge weight. After this, cursor[i] == row end.
__global__ __launch_bounds__(256) void k_fill(const int* __restrict__ src, const int* __restrict__ dst,
                                              const float* __restrict__ dis, int* __restrict__ cursor,
                                              int* __restrict__ csrc, float* __restrict__ cw) {
    int e = blockIdx.x * 256 + threadIdx.x;
    if (e >= NE) return;
    int s = src[e], d = dst[e];
    int slot = atomicAdd(&cursor[d], 1);
    csrc[slot] = s;
    cw[slot] = dis[s] * dis[d];
}

// C[M,128] = A[M,128] @ W[128,128], f32. Block: 64 rows x 128 cols, 256 thr, thread: 4x8.
__global__ __launch_bounds__(256) void k_gemm128(const float* __restrict__ A,
                                                 const float* __restrict__ W,
                                                 float* __restrict__ C, int M) {
    __shared__ float As[64][20];
    __shared__ float Bs[16][132];
    int tid = threadIdx.x;
    int r0 = blockIdx.x * 64;
    int tr = tid >> 4, tc = tid & 15;

    float acc[4][8];
#pragma unroll
    for (int i = 0; i < 4; ++i)
#pragma unroll
        for (int j = 0; j < 8; ++j) acc[i][j] = 0.f;

    int arow = tid >> 2, ac4 = (tid & 3) * 4;

    for (int k0 = 0; k0 < 128; k0 += 16) {
        float4 av = make_float4(0.f, 0.f, 0.f, 0.f);
        int gr = r0 + arow;
        if (gr < M) av = *(const float4*)&A[gr * 128 + k0 + ac4];
        *(float4*)&As[arow][ac4] = av;
#pragma unroll
        for (int t = 0; t < 2; ++t) {
            int idx = tid + t * 256;
            int bk = idx >> 5, bc4 = (idx & 31) * 4;
            *(float4*)&Bs[bk][bc4] = *(const float4*)&W[(k0 + bk) * 128 + bc4];
        }
        __syncthreads();
#pragma unroll
        for (int kk = 0; kk < 16; ++kk) {
            float a[4];
#pragma unroll
            for (int i = 0; i < 4; ++i) a[i] = As[tr * 4 + i][kk];
            float4 bv0 = *(float4*)&Bs[kk][tc * 8];
            float4 bv1 = *(float4*)&Bs[kk][tc * 8 + 4];
            float b[8] = {bv0.x, bv0.y, bv0.z, bv0.w, bv1.x, bv1.y, bv1.z, bv1.w};
#pragma unroll
            for (int i = 0; i < 4; ++i)
#pragma unroll
                for (int j = 0; j < 8; ++j) acc[i][j] = fmaf(a[i], b[j], acc[i][j]);
        }
        __syncthreads();
    }

#pragma unroll
    for (int i = 0; i < 4; ++i) {
        int gr = r0 + tr * 4 + i;
        if (gr < M) {
            float4 o0 = make_float4(acc[i][0], acc[i][1], acc[i][2], acc[i][3]);
            float4 o1 = make_float4(acc[i][4], acc[i][5], acc[i][6], acc[i][7]);
            *(float4*)&C[gr * 128 + tc * 8] = o0;
            *(float4*)&C[gr * 128 + tc * 8 + 4] = o1;
        }
    }
}

// Gather aggregation, 32 threads/node (float4 each). Fuses self-loop + bias +
// relu, and either writes the node feature or atomically accumulates the
// graph mean-pool sums (last layer).
template <int POOL>
__global__ __launch_bounds__(256) void k_gather(const float* __restrict__ h,
                                                const int* __restrict__ rowstart,
                                                const int* __restrict__ rowend,
                                                const int* __restrict__ csrc,
                                                const float* __restrict__ cw,
                                                const float* __restrict__ dis,
                                                const float* __restrict__ bias,
                                                float* __restrict__ outbuf,
                                                const int* __restrict__ batch,
                                                float* __restrict__ sums) {
    int t = blockIdx.x * 256 + threadIdx.x;
    int node = t >> 5;
    if (node >= NN) return;
    int f4 = t & 31;

    float d = dis[node];
    float w0 = d * d;
    float4 hv = ((const float4*)h)[node * 32 + f4];
    float4 acc = make_float4(hv.x * w0, hv.y * w0, hv.z * w0, hv.w * w0);

    int s = rowstart[node];
    int e = rowend[node];
    for (; s < e; ++s) {
        int sn = csrc[s];
        float w = cw[s];
        float4 v = ((const float4*)h)[sn * 32 + f4];
        acc.x = fmaf(v.x, w, acc.x);
        acc.y = fmaf(v.y, w, acc.y);
        acc.z = fmaf(v.z, w, acc.z);
        acc.w = fmaf(v.w, w, acc.w);
    }

    float4 b = ((const float4*)bias)[f4];
    acc.x = fmaxf(acc.x + b.x, 0.f);
    acc.y = fmaxf(acc.y + b.y, 0.f);
    acc.z = fmaxf(acc.z + b.z, 0.f);
    acc.w = fmaxf(acc.w + b.w, 0.f);

    if (POOL == 0) {
        ((float4*)outbuf)[node * 32 + f4] = acc;
    } else {
        int g = batch[node];
        float* o = sums + g * 128 + f4 * 4;
        atomicAdd(o + 0, acc.x);
        atomicAdd(o + 1, acc.y);
        atomicAdd(o + 2, acc.z);
        atomicAdd(o + 3, acc.w);
    }
}

// 512 blocks x 64 threads: pooled = sums/count; logits = pooled@Wf + bf; log_softmax
__global__ __launch_bounds__(64) void k_head(const float* __restrict__ sums,
                                             const float* __restrict__ counts,
                                             const float* __restrict__ Wf,
                                             const float* __restrict__ bf,
                                             float* __restrict__ out) {
    int g = blockIdx.x;
    int l = threadIdx.x;
    float inv = 1.0f / fmaxf(counts[g], 1.0f);
    float p0 = sums[g * 128 + l] * inv;
    float p1 = sums[g * 128 + 64 + l] * inv;
    float logit[10];
#pragma unroll
    for (int o = 0; o < 10; ++o) {
        float part = p0 * Wf[l * 10 + o] + p1 * Wf[(l + 64) * 10 + o];
#pragma unroll
        for (int s = 32; s > 0; s >>= 1) part += __shfl_xor(part, s);
        logit[o] = part + bf[o];
    }
    if (l == 0) {
        float m = logit[0];
#pragma unroll
        for (int o = 1; o < 10; ++o) m = fmaxf(m, logit[o]);
        float sum = 0.f;
#pragma unroll
        for (int o = 0; o < 10; ++o) sum += expf(logit[o] - m);
        float lse = m + logf(sum);
#pragma unroll
        for (int o = 0; o < 10; ++o) out[g * 10 + o] = logit[o] - lse;
    }
}

extern "C" void kernel_launch(void* const* d_in, const int* in_sizes, int n_in,
                              void* d_out, int out_size, void* d_ws, size_t ws_size,
                              hipStream_t stream) {
    const float* x     = (const float*)d_in[0];
    const int*   ei    = (const int*)d_in[1];
    const int*   batch = (const int*)d_in[2];
    const float* W0 = (const float*)d_in[3];
    const float* b0 = (const float*)d_in[4];
    const float* W1 = (const float*)d_in[5];
    const float* b1 = (const float*)d_in[6];
    const float* W2 = (const float*)d_in[7];
    const float* b2 = (const float*)d_in[8];
    const float* Wf = (const float*)d_in[9];
    const float* bf = (const float*)d_in[10];
    float* out = (float*)d_out;

    float* ws = (float*)d_ws;
    // layout (floats): [sums 65536][counts 512][in_deg 50048][gcur 64] = zeroed block
    float* sums    = ws;
    float* counts  = ws + 65536;
    int*   in_deg  = (int*)(ws + 66048);
    int*   gcur    = (int*)(ws + 116096);
    float* dis     = ws + 116160;
    int*   rowstart= (int*)(ws + 166208);
    int*   cursor  = (int*)(ws + 216256);
    int*   csr_src = (int*)(ws + 266304);
    float* csr_w   = ws + 866368;
    float* bufA    = ws + 1466432;
    float* bufB    = bufA + NN * DH;

    const int* src = ei;
    const int* dst = ei + NE;

    // --- CSR build + norms + pool counts ---
    k_zero<<<(116160 + 255) / 256, 256, 0, stream>>>(ws, 116160);
    k_hist<<<2344, 256, 0, stream>>>(dst, in_deg);
    k_counts<<<196, 256, 0, stream>>>(batch, counts);
    k_alloc<<<196, 256, 0, stream>>>(in_deg, gcur, rowstart, cursor, dis);
    k_fill<<<2344, 256, 0, stream>>>(src, dst, dis, cursor, csr_src, csr_w);
    // after k_fill, cursor[i] == row end

    // layer 0: x -> bufB (h@W0) -> bufA (aggregate+bias+relu)
    k_gemm128<<<(NN + 63) / 64, 256, 0, stream>>>(x, W0, bufB, NN);
    k_gather<0><<<6250, 256, 0, stream>>>(bufB, rowstart, cursor, csr_src, csr_w, dis, b0, bufA, batch, sums);

    // layer 1
    k_gemm128<<<(NN + 63) / 64, 256, 0, stream>>>(bufA, W1, bufB, NN);
    k_gather<0><<<6250, 256, 0, stream>>>(bufB, rowstart, cursor, csr_src, csr_w, dis, b1, bufA, batch, sums);

    // layer 2: fuse bias+relu+mean-pool accumulate
    k_gemm128<<<(NN + 63) / 64, 256, 0, stream>>>(bufA, W2, bufB, NN);
    k_gather<1><<<6250, 256, 0, stream>>>(bufB, rowstart, cursor, csr_src, csr_w, dis, b2, nullptr, batch, sums);

    k_head<<<512, 64, 0, stream>>>(sums, counts, Wf, bf, out);
}

// Round 3
// 408.216 us; speedup vs baseline: 8.1981x; 1.0926x over previous
//
#include <hip/hip_runtime.h>
#include <hip/hip_bf16.h>

#define NN 50000
#define NE 600000
#define NG 512

typedef __attribute__((ext_vector_type(8))) short bf16x8;
typedef __attribute__((ext_vector_type(4))) float f32x4;

__device__ __forceinline__ float bf_lo(unsigned u) {
    unsigned v = u << 16;
    return __builtin_bit_cast(float, v);
}
__device__ __forceinline__ float bf_hi(unsigned u) {
    unsigned v = u & 0xFFFF0000u;
    return __builtin_bit_cast(float, v);
}
__device__ __forceinline__ unsigned f2bf(float f) {  // RNE, returns in low 16 bits
    unsigned u = __builtin_bit_cast(unsigned, f);
    return (u + 0x7FFFu + ((u >> 16) & 1u)) >> 16;
}

__global__ __launch_bounds__(256) void k_zero(float* p, int n) {
    int i = blockIdx.x * 256 + threadIdx.x;
    if (i < n) p[i] = 0.0f;
}

__global__ __launch_bounds__(256) void k_hist(const int* __restrict__ dst, int* __restrict__ deg) {
    int e = blockIdx.x * 256 + threadIdx.x;
    if (e < NE) atomicAdd(&deg[dst[e]], 1);
}

__global__ __launch_bounds__(256) void k_counts(const int* __restrict__ batch, float* __restrict__ counts) {
    int i = blockIdx.x * 256 + threadIdx.x;
    if (i < NN) atomicAdd(&counts[batch[i]], 1.0f);
}

__global__ __launch_bounds__(256) void k_alloc(const int* __restrict__ deg, int* __restrict__ gcur,
                                               int* __restrict__ rowstart, int* __restrict__ cursor,
                                               float* __restrict__ dis) {
    int i = blockIdx.x * 256 + threadIdx.x;
    if (i >= NN) return;
    int d = deg[i];
    int st = atomicAdd(gcur, d);
    rowstart[i] = st;
    cursor[i] = st;
    dis[i] = 1.0f / sqrtf((float)(d + 1));
}

__global__ __launch_bounds__(256) void k_fill(const int* __restrict__ src, const int* __restrict__ dst,
                                              const float* __restrict__ dis, int* __restrict__ cursor,
                                              int* __restrict__ csrc, float* __restrict__ cw) {
    int e = blockIdx.x * 256 + threadIdx.x;
    if (e >= NE) return;
    int s = src[e], d = dst[e];
    int slot = atomicAdd(&cursor[d], 1);
    csrc[slot] = s;
    cw[slot] = dis[s] * dis[d];
}

// x (f32) -> bf16 packed
__global__ __launch_bounds__(256) void k_cvt_x(const float4* __restrict__ in, uint2* __restrict__ out, int n4) {
    int i = blockIdx.x * 256 + threadIdx.x;
    if (i >= n4) return;
    float4 v = in[i];
    uint2 o;
    o.x = f2bf(v.x) | (f2bf(v.y) << 16);
    o.y = f2bf(v.z) | (f2bf(v.w) << 16);
    out[i] = o;
}

// W[k][c] f32 -> Wt[c][k] bf16, for 3 weight matrices
__global__ __launch_bounds__(256) void k_cvt_w(const float* __restrict__ W0, const float* __restrict__ W1,
                                               const float* __restrict__ W2, unsigned short* __restrict__ Wt) {
    int idx = blockIdx.x * 256 + threadIdx.x;
    if (idx >= 3 * 16384) return;
    int m = idx >> 14;
    int r = idx & 16383;
    int k = r >> 7, c = r & 127;
    const float* W = (m == 0) ? W0 : (m == 1) ? W1 : W2;
    Wt[m * 16384 + c * 128 + k] = (unsigned short)f2bf(W[k * 128 + c]);
}

// C[M,128](bf16) = A[M,128](bf16) @ W[128,128], W given transposed Wt[col][k] bf16.
// 256 thr = 4 waves; each wave: 16 rows x 128 cols via mfma_f32_16x16x32_bf16.
__global__ __launch_bounds__(256) void k_gemm_mfma(const unsigned short* __restrict__ A,
                                                   const unsigned short* __restrict__ Wt,
                                                   unsigned short* __restrict__ C, int M) {
    int wave = threadIdx.x >> 6;
    int lane = threadIdx.x & 63;
    int rowbase = blockIdx.x * 64 + wave * 16;
    int lr = lane & 15;   // A row within tile / B col within tile
    int kg = lane >> 4;   // k-group 0..3 (8 elems each)

    int arow = rowbase + lr;
    if (arow >= M) arow = M - 1;
    bf16x8 a[4];
#pragma unroll
    for (int kt = 0; kt < 4; ++kt)
        a[kt] = *(const bf16x8*)&A[arow * 128 + kt * 32 + kg * 8];

    f32x4 acc[8];
#pragma unroll
    for (int nt = 0; nt < 8; ++nt) acc[nt] = (f32x4){0.f, 0.f, 0.f, 0.f};

#pragma unroll
    for (int nt = 0; nt < 8; ++nt) {
        const unsigned short* wp = &Wt[(nt * 16 + lr) * 128 + kg * 8];
#pragma unroll
        for (int kt = 0; kt < 4; ++kt) {
            bf16x8 b = *(const bf16x8*)&wp[kt * 32];
            acc[nt] = __builtin_amdgcn_mfma_f32_16x16x32_bf16(a[kt], b, acc[nt], 0, 0, 0);
        }
    }

    int crow0 = rowbase + (lane >> 4) * 4;  // C/D: col = lane&15, row = (lane>>4)*4 + r
#pragma unroll
    for (int nt = 0; nt < 8; ++nt) {
#pragma unroll
        for (int r = 0; r < 4; ++r) {
            int gr = crow0 + r;
            if (gr < M) C[gr * 128 + nt * 16 + lr] = (unsigned short)f2bf(acc[nt][r]);
        }
    }
}

// Gather aggregation over bf16 features, 32 threads/node (uint2 = 4 bf16 each).
// f32 accumulate; fuses self-loop + bias + relu; POOL=1 accumulates graph sums.
template <int POOL>
__global__ __launch_bounds__(256) void k_gather(const uint2* __restrict__ h,
                                                const int* __restrict__ rowstart,
                                                const int* __restrict__ rowend,
                                                const int* __restrict__ csrc,
                                                const float* __restrict__ cw,
                                                const float* __restrict__ dis,
                                                const float* __restrict__ bias,
                                                uint2* __restrict__ outbuf,
                                                const int* __restrict__ batch,
                                                float* __restrict__ sums) {
    int t = blockIdx.x * 256 + threadIdx.x;
    int node = t >> 5;
    if (node >= NN) return;
    int f = t & 31;  // cols f*4 .. f*4+3

    float d = dis[node];
    float w0 = d * d;
    uint2 hv = h[node * 32 + f];
    float a0 = bf_lo(hv.x) * w0;
    float a1 = bf_hi(hv.x) * w0;
    float a2 = bf_lo(hv.y) * w0;
    float a3 = bf_hi(hv.y) * w0;

    int s = rowstart[node];
    int e = rowend[node];
    for (; s < e; ++s) {
        int sn = csrc[s];
        float w = cw[s];
        uint2 v = h[sn * 32 + f];
        a0 = fmaf(bf_lo(v.x), w, a0);
        a1 = fmaf(bf_hi(v.x), w, a1);
        a2 = fmaf(bf_lo(v.y), w, a2);
        a3 = fmaf(bf_hi(v.y), w, a3);
    }

    float4 b = ((const float4*)bias)[f];
    a0 = fmaxf(a0 + b.x, 0.f);
    a1 = fmaxf(a1 + b.y, 0.f);
    a2 = fmaxf(a2 + b.z, 0.f);
    a3 = fmaxf(a3 + b.w, 0.f);

    if (POOL == 0) {
        uint2 o;
        o.x = f2bf(a0) | (f2bf(a1) << 16);
        o.y = f2bf(a2) | (f2bf(a3) << 16);
        outbuf[node * 32 + f] = o;
    } else {
        int g = batch[node];
        float* o = sums + g * 128 + f * 4;
        atomicAdd(o + 0, a0);
        atomicAdd(o + 1, a1);
        atomicAdd(o + 2, a2);
        atomicAdd(o + 3, a3);
    }
}

// 512 blocks x 64 threads: pooled = sums/count; logits = pooled@Wf + bf; log_softmax
__global__ __launch_bounds__(64) void k_head(const float* __restrict__ sums,
                                             const float* __restrict__ counts,
                                             const float* __restrict__ Wf,
                                             const float* __restrict__ bf,
                                             float* __restrict__ out) {
    int g = blockIdx.x;
    int l = threadIdx.x;
    float inv = 1.0f / fmaxf(counts[g], 1.0f);
    float p0 = sums[g * 128 + l] * inv;
    float p1 = sums[g * 128 + 64 + l] * inv;
    float logit[10];
#pragma unroll
    for (int o = 0; o < 10; ++o) {
        float part = p0 * Wf[l * 10 + o] + p1 * Wf[(l + 64) * 10 + o];
#pragma unroll
        for (int s = 32; s > 0; s >>= 1) part += __shfl_xor(part, s);
        logit[o] = part + bf[o];
    }
    if (l == 0) {
        float m = logit[0];
#pragma unroll
        for (int o = 1; o < 10; ++o) m = fmaxf(m, logit[o]);
        float sum = 0.f;
#pragma unroll
        for (int o = 0; o < 10; ++o) sum += expf(logit[o] - m);
        float lse = m + logf(sum);
#pragma unroll
        for (int o = 0; o < 10; ++o) out[g * 10 + o] = logit[o] - lse;
    }
}

extern "C" void kernel_launch(void* const* d_in, const int* in_sizes, int n_in,
                              void* d_out, int out_size, void* d_ws, size_t ws_size,
                              hipStream_t stream) {
    const float* x     = (const float*)d_in[0];
    const int*   ei    = (const int*)d_in[1];
    const int*   batch = (const int*)d_in[2];
    const float* W0 = (const float*)d_in[3];
    const float* b0 = (const float*)d_in[4];
    const float* W1 = (const float*)d_in[5];
    const float* b1 = (const float*)d_in[6];
    const float* W2 = (const float*)d_in[7];
    const float* b2 = (const float*)d_in[8];
    const float* Wf = (const float*)d_in[9];
    const float* bf = (const float*)d_in[10];
    float* out = (float*)d_out;

    float* ws = (float*)d_ws;
    // float-offset layout
    float* sums    = ws;                      // 65536
    float* counts  = ws + 65536;              // 512
    int*   in_deg  = (int*)(ws + 66048);      // 50048
    int*   gcur    = (int*)(ws + 116096);     // 64
    float* dis     = ws + 116160;             // 50048
    int*   rowstart= (int*)(ws + 166208);     // 50048
    int*   cursor  = (int*)(ws + 216256);     // 50048
    int*   csr_src = (int*)(ws + 266304);     // 600064
    float* csr_w   = ws + 866368;             // 600064
    unsigned short* Wt = (unsigned short*)(ws + 1466432);   // 3*16384 ushort = 24576 f
    unsigned short* bx = (unsigned short*)(ws + 1491008);   // 6.4M ushort = 3.2M f
    unsigned short* hA = (unsigned short*)(ws + 4691008);   // 3.2M f
    unsigned short* hB = (unsigned short*)(ws + 7891008);   // 3.2M f

    const int* src = ei;
    const int* dst = ei + NE;

    // --- CSR build + norms + pool counts + conversions ---
    k_zero<<<(116160 + 255) / 256, 256, 0, stream>>>(ws, 116160);
    k_hist<<<2344, 256, 0, stream>>>(dst, in_deg);
    k_counts<<<196, 256, 0, stream>>>(batch, counts);
    k_alloc<<<196, 256, 0, stream>>>(in_deg, gcur, rowstart, cursor, dis);
    k_fill<<<2344, 256, 0, stream>>>(src, dst, dis, cursor, csr_src, csr_w);
    k_cvt_x<<<6250, 256, 0, stream>>>((const float4*)x, (uint2*)bx, NN * 32);
    k_cvt_w<<<192, 256, 0, stream>>>(W0, W1, W2, Wt);

    const int GEMM_GRID = (NN + 63) / 64;

    // layer 0: bx -> hB (h@W0, bf16) -> hA (aggregate+bias+relu, bf16)
    k_gemm_mfma<<<GEMM_GRID, 256, 0, stream>>>(bx, Wt, hB, NN);
    k_gather<0><<<6250, 256, 0, stream>>>((const uint2*)hB, rowstart, cursor, csr_src, csr_w,
                                          dis, b0, (uint2*)hA, batch, sums);
    // layer 1
    k_gemm_mfma<<<GEMM_GRID, 256, 0, stream>>>(hA, Wt + 16384, hB, NN);
    k_gather<0><<<6250, 256, 0, stream>>>((const uint2*)hB, rowstart, cursor, csr_src, csr_w,
                                          dis, b1, (uint2*)hA, batch, sums);
    // layer 2: fuse bias+relu+mean-pool accumulate (f32 sums)
    k_gemm_mfma<<<GEMM_GRID, 256, 0, stream>>>(hA, Wt + 32768, hB, NN);
    k_gather<1><<<6250, 256, 0, stream>>>((const uint2*)hB, rowstart, cursor, csr_src, csr_w,
                                          dis, b2, nullptr, batch, sums);

    k_head<<<512, 64, 0, stream>>>(sums, counts, Wf, bf, out);
}